// Round 3
// baseline (136.350 us; speedup 1.0000x reference)
//
#include <hip/hip_runtime.h>
#include <math.h>

#define NN 2048
#define BB 64
#define DD 512
#define NSEL 512  // NN/4
#define IPB 8     // rows (i values) per gather block

// ---------------------------------------------------------------------------
// Kernel 1: per-row 5th-largest value (thr) for attention (rows 0..63) and
// att_off (rows 64..127). One wave (64 lanes) per row.
// ---------------------------------------------------------------------------
__device__ __forceinline__ void insert5(float v, float t[5]) {
  if (v > t[4]) {
    if (v > t[0])      { t[4]=t[3]; t[3]=t[2]; t[2]=t[1]; t[1]=t[0]; t[0]=v; }
    else if (v > t[1]) { t[4]=t[3]; t[3]=t[2]; t[2]=t[1]; t[1]=v; }
    else if (v > t[2]) { t[4]=t[3]; t[3]=t[2]; t[2]=v; }
    else if (v > t[3]) { t[4]=t[3]; t[3]=v; }
    else               { t[4]=v; }
  }
}

__global__ void thr_kernel(const float* __restrict__ att,
                           const float* __restrict__ aoff,
                           float* __restrict__ thr) {
  int blk  = blockIdx.x;                 // 0..127
  const float* src = (blk < BB) ? att : aoff;
  int row  = (blk < BB) ? blk : blk - BB;
  int lane = threadIdx.x;                // 0..63

  float t[5] = {-INFINITY, -INFINITY, -INFINITY, -INFINITY, -INFINITY};
  const float* rp = src + (size_t)row * NN;
  #pragma unroll
  for (int k = 0; k < NN / 64; ++k) insert5(rp[lane + 64 * k], t);

  for (int off = 1; off < 64; off <<= 1) {
    float b[5];
    #pragma unroll
    for (int k = 0; k < 5; ++k) b[k] = __shfl_xor(t[k], off, 64);
    float m[5];
    int ia = 0, ib = 0;
    #pragma unroll
    for (int k = 0; k < 5; ++k) {
      float av = t[ia], bv = b[ib];
      bool ta = (av >= bv);
      m[k] = ta ? av : bv;
      ia += ta ? 1 : 0;
      ib += ta ? 0 : 1;
    }
    #pragma unroll
    for (int k = 0; k < 5; ++k) t[k] = m[k];
  }
  if (lane == 0) thr[blk] = t[4];        // 5th largest (vals[:, PS])
}

// ---------------------------------------------------------------------------
// Kernel 2: key[n] = #(att[:,n] >= thr_att) + #(aoff[:,n] >= thr_off) == 2*M.
// ---------------------------------------------------------------------------
__global__ void mkey_kernel(const float* __restrict__ att,
                            const float* __restrict__ aoff,
                            const float* __restrict__ thr,
                            int* __restrict__ key) {
  int n = blockIdx.x * blockDim.x + threadIdx.x;
  if (n >= NN) return;
  int c = 0;
  #pragma unroll 16
  for (int b = 0; b < BB; ++b) c += (att[(size_t)b * NN + n] >= thr[b]) ? 1 : 0;
  #pragma unroll 16
  for (int b = 0; b < BB; ++b) c += (aoff[(size_t)b * NN + n] >= thr[BB + b]) ? 1 : 0;
  key[n] = c;
}

// ---------------------------------------------------------------------------
// Kernel 3: fully parallel stable descending counting-sort; emit top 512.
// rank(n) = #(key > k) + #(same key, earlier chunk) + #(same key, earlier in
// chunk). Matches jnp.argsort(-M) stable semantics exactly.
// ---------------------------------------------------------------------------
__global__ void __launch_bounds__(1024)
topm_kernel(const int* __restrict__ key,
            int* __restrict__ top_m,
            float* __restrict__ out_tail) {
  __shared__ int kl[NN];
  __shared__ int chist[32][132];
  __shared__ int htot[132];
  __shared__ int gbase[132];
  int t = threadIdx.x;             // 0..1023

  for (int i = t; i < 32 * 132; i += 1024) (&chist[0][0])[i] = 0;
  __syncthreads();

  int k0 = key[t];
  int k1 = key[t + 1024];
  kl[t] = k0;
  kl[t + 1024] = k1;
  int c0 = t >> 6;
  int c1 = 16 + (t >> 6);
  atomicAdd(&chist[c0][k0], 1);
  atomicAdd(&chist[c1][k1], 1);
  __syncthreads();

  if (t < 129) {
    int run = 0;
    #pragma unroll 4
    for (int c = 0; c < 32; ++c) { int v = chist[c][t]; chist[c][t] = run; run += v; }
    htot[t] = run;
  }
  __syncthreads();
  if (t == 0) {
    int acc = 0;
    for (int k = 128; k >= 0; --k) { gbase[k] = acc; acc += htot[k]; }
  }
  __syncthreads();

  int n0 = t, n1 = t + 1024;
  int pre0 = 0;
  for (int j = c0 * 64; j < n0; ++j) pre0 += (kl[j] == k0) ? 1 : 0;
  int pre1 = 0;
  for (int j = c1 * 64; j < n1; ++j) pre1 += (kl[j] == k1) ? 1 : 0;

  int r0 = gbase[k0] + chist[c0][k0] + pre0;
  int r1 = gbase[k1] + chist[c1][k1] + pre1;
  if (r0 < NSEL) { top_m[r0] = n0; out_tail[r0] = (float)n0; }
  if (r1 < NSEL) { top_m[r1] = n1; out_tail[r1] = (float)n1; }
}

// ---------------------------------------------------------------------------
// Kernel 4 (fused, pipelined): each block handles IPB=8 consecutive i for one
// batch b. Double-buffered LDS row staging with register prefetch:
//   iter k: prefetch row k+1 -> regs | x-copy row k | gather buf[k&1] -> ys
//           | regs -> buf[(k+1)&1] | ONE __syncthreads
// cols[] loaded once per block. ys written as float2.
// ---------------------------------------------------------------------------
__global__ void __launch_bounds__(256)
gather_kernel(const float* __restrict__ x,
              const float* __restrict__ y,
              const int* __restrict__ top_m,
              float* __restrict__ xs,
              float* __restrict__ ys) {
  __shared__ float row[2][NN];
  __shared__ int cols[NSEL];
  int blk = blockIdx.x;            // 0..BB*64-1
  int b  = blk >> 6;
  int i0 = (blk & 63) * IPB;
  int t  = threadIdx.x;            // 0..255

  for (int j = t; j < NSEL; j += 256) cols[j] = top_m[j];

  const float* ybase = y + (size_t)b * NN * NN;

  // prologue: row i0 -> buf0
  float4 pre0, pre1;
  {
    int r = top_m[i0];
    const float4* src = (const float4*)(ybase + (size_t)r * NN);
    pre0 = src[t];
    pre1 = src[t + 256];
  }
  {
    float4* b0 = (float4*)row[0];
    b0[t]       = pre0;
    b0[t + 256] = pre1;
  }
  __syncthreads();   // buf0 + cols ready

  #pragma unroll
  for (int k = 0; k < IPB; ++k) {
    int cur = k & 1;
    // prefetch next y row into registers (latency hides under gather/x-copy)
    if (k + 1 < IPB) {
      int rn = top_m[i0 + k + 1];
      const float4* src = (const float4*)(ybase + (size_t)rn * NN);
      pre0 = src[t];
      pre1 = src[t + 256];
    }
    // x row copy (threads 0..127, float4)
    int rk = top_m[i0 + k];
    if (t < 128) {
      const float4* xsrc = (const float4*)(x + ((size_t)b * NN + rk) * DD);
      float4*       xdst = (float4*)(xs + ((size_t)b * NSEL + (i0 + k)) * DD);
      xdst[t] = xsrc[t];
    }
    // gather 2 columns per thread, float2 store
    {
      const float* rw = row[cur];
      float2 o;
      o.x = rw[cols[2 * t]];
      o.y = rw[cols[2 * t + 1]];
      float2* dst = (float2*)(ys + ((size_t)b * NSEL + (i0 + k)) * DD);
      dst[t] = o;
    }
    // stage prefetched row into the other buffer
    if (k + 1 < IPB) {
      float4* bn = (float4*)row[cur ^ 1];
      bn[t]       = pre0;
      bn[t + 256] = pre1;
    }
    __syncthreads();   // one barrier per row
  }
}

// ---------------------------------------------------------------------------
extern "C" void kernel_launch(void* const* d_in, const int* in_sizes, int n_in,
                              void* d_out, int out_size, void* d_ws, size_t ws_size,
                              hipStream_t stream) {
  const float* x    = (const float*)d_in[0];   // (64, 2048, 512)
  const float* y    = (const float*)d_in[1];   // (64, 2048, 2048)
  const float* att  = (const float*)d_in[2];   // (64, 2048)
  const float* aoff = (const float*)d_in[3];   // (64, 2048)

  float* out = (float*)d_out;
  float* xs   = out;                                    // 64*512*512
  float* ysel = out + (size_t)BB * NSEL * DD;           // 64*512*512
  float* tail = ysel + (size_t)BB * NSEL * NSEL;        // 512 floats

  float* thr   = (float*)d_ws;                          // 128 floats
  int*   key   = (int*)d_ws + 128;                      // 2048 ints
  int*   top_m = (int*)d_ws + 128 + NN;                 // 512 ints

  hipLaunchKernelGGL(thr_kernel, dim3(2 * BB), dim3(64), 0, stream, att, aoff, thr);
  hipLaunchKernelGGL(mkey_kernel, dim3(NN / 256), dim3(256), 0, stream, att, aoff, thr, key);
  hipLaunchKernelGGL(topm_kernel, dim3(1), dim3(1024), 0, stream, key, top_m, tail);
  hipLaunchKernelGGL(gather_kernel, dim3(BB * (NSEL / IPB)), dim3(256), 0, stream,
                     x, y, top_m, xs, ysel);
}

// Round 5
// 129.832 us; speedup vs baseline: 1.0502x; 1.0502x over previous
//
#include <hip/hip_runtime.h>
#include <math.h>

#define NN 2048
#define BB 64
#define DD 512
#define NSEL 512  // NN/4

typedef float fx4 __attribute__((ext_vector_type(4)));

// ---------------------------------------------------------------------------
// Kernel 1: per-row 5th-largest value (thr) for attention (rows 0..63) and
// att_off (rows 64..127). One wave (64 lanes) per row.
// ---------------------------------------------------------------------------
__device__ __forceinline__ void insert5(float v, float t[5]) {
  if (v > t[4]) {
    if (v > t[0])      { t[4]=t[3]; t[3]=t[2]; t[2]=t[1]; t[1]=t[0]; t[0]=v; }
    else if (v > t[1]) { t[4]=t[3]; t[3]=t[2]; t[2]=t[1]; t[1]=v; }
    else if (v > t[2]) { t[4]=t[3]; t[3]=t[2]; t[2]=v; }
    else if (v > t[3]) { t[4]=t[3]; t[3]=v; }
    else               { t[4]=v; }
  }
}

__global__ void thr_kernel(const float* __restrict__ att,
                           const float* __restrict__ aoff,
                           float* __restrict__ thr) {
  int blk  = blockIdx.x;                 // 0..127
  const float* src = (blk < BB) ? att : aoff;
  int row  = (blk < BB) ? blk : blk - BB;
  int lane = threadIdx.x;                // 0..63

  float t[5] = {-INFINITY, -INFINITY, -INFINITY, -INFINITY, -INFINITY};
  const float* rp = src + (size_t)row * NN;
  #pragma unroll
  for (int k = 0; k < NN / 64; ++k) insert5(rp[lane + 64 * k], t);

  for (int off = 1; off < 64; off <<= 1) {
    float b[5];
    #pragma unroll
    for (int k = 0; k < 5; ++k) b[k] = __shfl_xor(t[k], off, 64);
    float m[5];
    int ia = 0, ib = 0;
    #pragma unroll
    for (int k = 0; k < 5; ++k) {
      float av = t[ia], bv = b[ib];
      bool ta = (av >= bv);
      m[k] = ta ? av : bv;
      ia += ta ? 1 : 0;
      ib += ta ? 0 : 1;
    }
    #pragma unroll
    for (int k = 0; k < 5; ++k) t[k] = m[k];
  }
  if (lane == 0) thr[blk] = t[4];        // 5th largest (vals[:, PS])
}

// ---------------------------------------------------------------------------
// Kernel 2: key[n] = #(att[:,n] >= thr_att) + #(aoff[:,n] >= thr_off) == 2*M.
// 32 blocks x 64 threads: one column per thread.
// ---------------------------------------------------------------------------
__global__ void mkey_kernel(const float* __restrict__ att,
                            const float* __restrict__ aoff,
                            const float* __restrict__ thr,
                            int* __restrict__ key) {
  int n = blockIdx.x * 64 + threadIdx.x;
  if (n >= NN) return;
  int c = 0;
  #pragma unroll 16
  for (int b = 0; b < BB; ++b) c += (att[(size_t)b * NN + n] >= thr[b]) ? 1 : 0;
  #pragma unroll 16
  for (int b = 0; b < BB; ++b) c += (aoff[(size_t)b * NN + n] >= thr[BB + b]) ? 1 : 0;
  key[n] = c;
}

// ---------------------------------------------------------------------------
// Kernel 3: fully parallel stable descending counting-sort; emit top 512.
// rank(n) = #(key > k) + #(same key, earlier chunk) + #(same key, earlier in
// chunk). Matches jnp.argsort(-M) stable semantics exactly.
// ---------------------------------------------------------------------------
__global__ void __launch_bounds__(1024)
topm_kernel(const int* __restrict__ key,
            int* __restrict__ top_m,
            float* __restrict__ out_tail) {
  __shared__ int kl[NN];
  __shared__ int chist[32][132];
  __shared__ int htot[132];
  __shared__ int gbase[132];
  int t = threadIdx.x;             // 0..1023

  for (int i = t; i < 32 * 132; i += 1024) (&chist[0][0])[i] = 0;
  __syncthreads();

  int k0 = key[t];
  int k1 = key[t + 1024];
  kl[t] = k0;
  kl[t + 1024] = k1;
  int c0 = t >> 6;
  int c1 = 16 + (t >> 6);
  atomicAdd(&chist[c0][k0], 1);
  atomicAdd(&chist[c1][k1], 1);
  __syncthreads();

  if (t < 129) {
    int run = 0;
    #pragma unroll 4
    for (int c = 0; c < 32; ++c) { int v = chist[c][t]; chist[c][t] = run; run += v; }
    htot[t] = run;
  }
  __syncthreads();
  if (t == 0) {
    int acc = 0;
    for (int k = 128; k >= 0; --k) { gbase[k] = acc; acc += htot[k]; }
  }
  __syncthreads();

  int n0 = t, n1 = t + 1024;
  int pre0 = 0;
  for (int j = c0 * 64; j < n0; ++j) pre0 += (kl[j] == k0) ? 1 : 0;
  int pre1 = 0;
  for (int j = c1 * 64; j < n1; ++j) pre1 += (kl[j] == k1) ? 1 : 0;

  int r0 = gbase[k0] + chist[c0][k0] + pre0;
  int r1 = gbase[k1] + chist[c1][k1] + pre1;
  if (r0 < NSEL) { top_m[r0] = n0; out_tail[r0] = (float)n0; }
  if (r1 < NSEL) { top_m[r1] = n1; out_tail[r1] = (float)n1; }
}

// ---------------------------------------------------------------------------
// Kernel 4 (fused, per-wave, barrier-free): grid = 64b x 16 = 1024 blocks,
// 256 threads. Each WAVE owns a private 8KB LDS row buffer and handles 8
// consecutive i rows: reg-prefetch next y row (nontemporal) | commit regs ->
// own LDS | x row copy (nt) | gather 8 cols/lane from LDS | nt fx4 stores.
// No __syncthreads in the loop (wave-private buffers; vmcnt/lgkmcnt only).
// All touch-once streams use nontemporal hints to keep L2 clean.
// ---------------------------------------------------------------------------
__global__ void __launch_bounds__(256)
gather_kernel(const float* __restrict__ x,
              const float* __restrict__ y,
              const int* __restrict__ top_m,
              float* __restrict__ xs,
              float* __restrict__ ys) {
  __shared__ float rowbuf[4][NN];   // 32KB: one 8KB row per wave
  __shared__ int cols[NSEL];        // == top_m (rows ARE col indices)
  int t = threadIdx.x;
  int w = t >> 6, lane = t & 63;
  int blk = blockIdx.x;             // 0..1023
  int b = blk >> 4;
  int iblk = blk & 15;

  cols[t]       = top_m[t];
  cols[t + 256] = top_m[t + 256];
  __syncthreads();                  // the only block barrier

  float* myrow = rowbuf[w];
  int i0 = iblk * 32 + w * 8;       // this wave's 8 rows: i0..i0+7
  const float* ybase = y + (size_t)b * NN * NN;

  fx4 pr[8];
  {
    int r = cols[i0];
    const fx4* src = (const fx4*)(ybase + (size_t)r * NN);
    #pragma unroll
    for (int j = 0; j < 8; ++j)
      pr[j] = __builtin_nontemporal_load(&src[lane + 64 * j]);
  }

  #pragma unroll
  for (int k = 0; k < 8; ++k) {
    int i = i0 + k;
    // commit prefetched row k into this wave's LDS buffer
    {
      fx4* mb = (fx4*)myrow;
      #pragma unroll
      for (int j = 0; j < 8; ++j) mb[lane + 64 * j] = pr[j];
    }
    // issue prefetch of row k+1 (latency hides under x-copy + gather)
    if (k < 7) {
      int rn = cols[i + 1];
      const fx4* src = (const fx4*)(ybase + (size_t)rn * NN);
      #pragma unroll
      for (int j = 0; j < 8; ++j)
        pr[j] = __builtin_nontemporal_load(&src[lane + 64 * j]);
    }
    // x row copy (2KB, nt both ways)
    {
      int r = cols[i];
      const fx4* xsrc = (const fx4*)(x + ((size_t)b * NN + r) * DD);
      fx4*       xdst = (fx4*)(xs + ((size_t)b * NSEL + i) * DD);
      #pragma unroll
      for (int j = 0; j < 2; ++j) {
        fx4 v = __builtin_nontemporal_load(&xsrc[lane + 64 * j]);
        __builtin_nontemporal_store(v, &xdst[lane + 64 * j]);
      }
    }
    // gather: lane handles output cols 8*lane .. 8*lane+7 (contiguous 32B)
    {
      float o[8];
      #pragma unroll
      for (int j = 0; j < 8; ++j) o[j] = myrow[cols[8 * lane + j]];
      fx4* dst = (fx4*)(ys + ((size_t)b * NSEL + i) * DD);
      fx4 o0 = {o[0], o[1], o[2], o[3]};
      fx4 o1 = {o[4], o[5], o[6], o[7]};
      __builtin_nontemporal_store(o0, &dst[2 * lane]);
      __builtin_nontemporal_store(o1, &dst[2 * lane + 1]);
    }
  }
}

// ---------------------------------------------------------------------------
extern "C" void kernel_launch(void* const* d_in, const int* in_sizes, int n_in,
                              void* d_out, int out_size, void* d_ws, size_t ws_size,
                              hipStream_t stream) {
  const float* x    = (const float*)d_in[0];   // (64, 2048, 512)
  const float* y    = (const float*)d_in[1];   // (64, 2048, 2048)
  const float* att  = (const float*)d_in[2];   // (64, 2048)
  const float* aoff = (const float*)d_in[3];   // (64, 2048)

  float* out = (float*)d_out;
  float* xs   = out;                                    // 64*512*512
  float* ysel = out + (size_t)BB * NSEL * DD;           // 64*512*512
  float* tail = ysel + (size_t)BB * NSEL * NSEL;        // 512 floats

  float* thr   = (float*)d_ws;                          // 128 floats
  int*   key   = (int*)d_ws + 128;                      // 2048 ints
  int*   top_m = (int*)d_ws + 128 + NN;                 // 512 ints

  hipLaunchKernelGGL(thr_kernel, dim3(2 * BB), dim3(64), 0, stream, att, aoff, thr);
  hipLaunchKernelGGL(mkey_kernel, dim3(32), dim3(64), 0, stream, att, aoff, thr, key);
  hipLaunchKernelGGL(topm_kernel, dim3(1), dim3(1024), 0, stream, key, top_m, tail);
  hipLaunchKernelGGL(gather_kernel, dim3(BB * 16), dim3(256), 0, stream,
                     x, y, top_m, xs, ysel);
}